// Round 23
// baseline (1108.074 us; speedup 1.0000x reference)
//
#include <hip/hip_runtime.h>

#define NN 6000
#define HH 256
#define LL 10
#define KX 30
#define PP 128
#define EE (NN * KX)
#define KPADU 512    // upd BT row length
#define RPADU 520    // upd A row stride (ushorts)
#define RPQ 264      // pq A-tile row stride (ushorts)
#define RH 264       // hsh row stride (ushorts)
#define NBINS 1024
#define BINSCALE 32768.0f   // 2^15: exact fp32 scale; covers d2 < 0.03125
#define CAP 64
#define ESPL 4       // edge-split groups per dst
#define DPB 2        // dst per msg_edge block

typedef __attribute__((ext_vector_type(8))) short short8;
typedef __attribute__((ext_vector_type(4))) float f32x4;

__device__ __forceinline__ unsigned short f2bf(float x) {
  union { float f; unsigned u; } v; v.f = x;
  return (unsigned short)((v.u + 0x7fffu + ((v.u >> 16) & 1u)) >> 16);
}
__device__ __forceinline__ float bf2f(unsigned short u) {
  union { unsigned u32; float f; } v; v.u32 = ((unsigned)u) << 16; return v.f;
}

// --------------------------------------------------------- pos -> float4
__global__ __launch_bounds__(256) void pos4_kernel(
    const float* __restrict__ pos, float4* __restrict__ pos4) {
  const int j = blockIdx.x * 256 + threadIdx.x;
  if (j >= NN) return;
  float4 p; p.x = pos[j * 3 + 0]; p.y = pos[j * 3 + 1]; p.z = pos[j * 3 + 2];
  p.w = 0.f;
  pos4[j] = p;
}

// ---------------------------------------------------------------- kNN
__global__ __launch_bounds__(256) void knn_kernel(
    const float4* __restrict__ pos4, const float* __restrict__ box,
    int* __restrict__ nbr, float* __restrict__ ea, int* __restrict__ counts) {
  __shared__ int hist[NBINS];
  __shared__ int sum4[256];
  __shared__ unsigned long long cand[CAP];
  __shared__ int cnt;
  __shared__ float Tsh;
  __shared__ float wvv[4];
  __shared__ int wvi[4];
  const int a = blockIdx.x, tid = threadIdx.x;
  const int lane = tid & 63, wv = tid >> 6;
  const float bx = box[0], by = box[1], bz = box[2];
  const float ibx = 1.0f / bx, iby = 1.0f / by, ibz = 1.0f / bz;
  const float4 pa = pos4[a];
  const float pax = pa.x, pay = pa.y, paz = pa.z;
  for (int i = tid; i < NBINS; i += 256) hist[i] = 0;
  if (tid == 0) cnt = 0;
  __syncthreads();
  float v[24];
#pragma unroll
  for (int q = 0; q < 24; ++q) {
    int j = tid + (q << 8);
    float d2 = 3e38f;
    if (j < NN && j != a) {
      float4 pj = pos4[j];
      float dx = pax - pj.x; dx -= rintf(dx * ibx) * bx;
      float dy = pay - pj.y; dy -= rintf(dy * iby) * by;
      float dz = paz - pj.z; dz -= rintf(dz * ibz) * bz;
      d2 = dx * dx + dy * dy + dz * dz;
    }
    v[q] = d2;
    if (d2 < 0.03125f) atomicAdd(&hist[(int)(d2 * BINSCALE)], 1);
  }
  __syncthreads();
  sum4[tid] = hist[tid * 4 + 0] + hist[tid * 4 + 1] +
              hist[tid * 4 + 2] + hist[tid * 4 + 3];
  __syncthreads();
  if (wv == 0) {
    int loc = sum4[lane * 4 + 0] + sum4[lane * 4 + 1] +
              sum4[lane * 4 + 2] + sum4[lane * 4 + 3];
    int inc = loc;
#pragma unroll
    for (int o = 1; o < 64; o <<= 1) {
      int t = __shfl_up(inc, o, 64);
      if (lane >= o) inc += t;
    }
    unsigned long long m = __ballot(inc >= KX);
    if (m == 0) {
      if (lane == 0) Tsh = -1.f;
    } else {
      int l0 = __ffsll(m) - 1;
      if (lane == l0) {
        int run = inc - loc;
        int B = l0 * 16;
        for (int i = 0; i < 16; ++i) {
          run += hist[l0 * 16 + i];
          if (run >= KX) { B = l0 * 16 + i; break; }
        }
        Tsh = (float)(B + 1) * (1.0f / BINSCALE);
      }
    }
  }
  __syncthreads();
  const float T = Tsh;
  if (T > 0.f) {
#pragma unroll
    for (int q = 0; q < 24; ++q) {
      if (v[q] < T) {
        int idx = atomicAdd(&cnt, 1);
        if (idx < CAP)
          cand[idx] = ((unsigned long long)__float_as_uint(v[q]) << 32) |
                      (unsigned)(tid + (q << 8));
      }
    }
    __syncthreads();
  }
  const int nc = cnt;
  const bool fast = (T > 0.f) && (nc >= KX) && (nc <= CAP);
  if (fast) {
    if (wv == 0) {
      unsigned long long key = (lane < nc) ? cand[lane] : ~0ull;
#pragma unroll
      for (int k = 2; k <= 64; k <<= 1) {
#pragma unroll
        for (int j = 32; j >= 1; j >>= 1) {
          if (j >= k) continue;
          unsigned long long other = __shfl_xor(key, j, 64);
          bool lower = ((lane & j) == 0);
          bool asc = ((lane & k) == 0);
          unsigned long long mn = (key < other) ? key : other;
          unsigned long long mx = (key < other) ? other : key;
          key = (lower == asc) ? mn : mx;
        }
      }
      if (lane < KX) {
        int b = (int)(key & 0xffffffffu);
        float d2 = __uint_as_float((unsigned)(key >> 32));
        float4 pb = pos4[b];
        float dx = pax - pb.x; dx -= rintf(dx * ibx) * bx;
        float dy = pay - pb.y; dy -= rintf(dy * iby) * by;
        float dz = paz - pb.z; dz -= rintf(dz * ibz) * bz;
        nbr[a * KX + lane] = b;
        float4 e4; e4.x = dx; e4.y = dy; e4.z = dz; e4.w = sqrtf(d2);
        *(float4*)&ea[(a * KX + lane) * 4] = e4;
        atomicAdd(&counts[b], 1);
      }
    }
  } else {
    // deterministic fallback: original 30-round argmin
    float lmin = v[0]; int larg = tid;
#pragma unroll
    for (int q = 1; q < 24; ++q) {
      int j = tid + (q << 8);
      if (v[q] < lmin) { lmin = v[q]; larg = j; }
    }
    for (int r = 0; r < KX; ++r) {
      float m = lmin; int ar = larg;
#pragma unroll
      for (int o = 1; o < 64; o <<= 1) {
        float m2 = __shfl_xor(m, o, 64);
        int a2 = __shfl_xor(ar, o, 64);
        if (m2 < m || (m2 == m && a2 < ar)) { m = m2; ar = a2; }
      }
      if (lane == 0) { wvv[wv] = m; wvi[wv] = ar; }
      __syncthreads();
      float gm = wvv[0]; int ga = wvi[0];
#pragma unroll
      for (int w2 = 1; w2 < 4; ++w2) {
        float m2 = wvv[w2]; int a2 = wvi[w2];
        if (m2 < gm || (m2 == gm && a2 < ga)) { gm = m2; ga = a2; }
      }
      if (tid == 0) {
        int b = ga;
        nbr[a * KX + r] = b;
        float4 pb = pos4[b];
        float dx = pax - pb.x; dx -= rintf(dx * ibx) * bx;
        float dy = pay - pb.y; dy -= rintf(dy * iby) * by;
        float dz = paz - pb.z; dz -= rintf(dz * ibz) * bz;
        float4 e4; e4.x = dx; e4.y = dy; e4.z = dz; e4.w = sqrtf(gm);
        *(float4*)&ea[(a * KX + r) * 4] = e4;
        atomicAdd(&counts[b], 1);
      }
      if ((ga & 255) == tid) {
        const int qq = ga >> 8;
#pragma unroll
        for (int q = 0; q < 24; ++q) if (q == qq) v[q] = 3e38f;
        lmin = v[0]; larg = tid;
#pragma unroll
        for (int q = 1; q < 24; ++q) {
          int j = tid + (q << 8);
          if (v[q] < lmin) { lmin = v[q]; larg = j; }
        }
      }
      __syncthreads();
    }
  }
}

// ------------------------------------------------- CSR build (deterministic)
__global__ __launch_bounds__(256) void offsets_kernel(
    const int* __restrict__ counts, int* __restrict__ offs, float* __restrict__ invd) {
  __shared__ int ssum[256];
  const int t = threadIdx.x;
  const int lo = t * 24;
  int hi = lo + 24; if (hi > NN) hi = NN;
  int s = 0;
  for (int i = lo; i < hi; ++i) s += counts[i];
  ssum[t] = s;
  __syncthreads();
  for (int o = 1; o < 256; o <<= 1) {
    int v2 = (t >= o) ? ssum[t - o] : 0;
    __syncthreads();
    ssum[t] += v2;
    __syncthreads();
  }
  int run = ssum[t] - s;
  for (int i = lo; i < hi; ++i) { offs[i] = run; run += counts[i]; }
  if (t == 255) offs[NN] = run;
  for (int i = t; i < NN; i += 256) {
    float c = (float)counts[i];
    invd[i] = 1.0f / fmaxf(c, 1.0f);
  }
}

__global__ __launch_bounds__(256) void scatter_kernel(
    const int* __restrict__ nbr, const int* __restrict__ offs,
    int* __restrict__ cursor, int* __restrict__ elist) {
  const int e = blockIdx.x * 256 + threadIdx.x;
  if (e >= EE) return;
  const int d = nbr[e];
  const int slot = offs[d] + atomicAdd(&cursor[d], 1);
  elist[slot] = e;
}

// one 64-lane wave per dst: register bitonic sort of the (<=64) run.
__global__ __launch_bounds__(256) void sortlists_kernel(
    const int* __restrict__ offs, int* __restrict__ elist) {
  const int wv = threadIdx.x >> 6, lane = threadIdx.x & 63;
  const int d = blockIdx.x * 4 + wv;
  if (d >= NN) return;
  const int s0 = offs[d], s1 = offs[d + 1];
  const int n = s1 - s0;
  if (n <= 1) return;
  if (n <= 64) {
    int key = (lane < n) ? elist[s0 + lane] : 0x7fffffff;
#pragma unroll
    for (int k = 2; k <= 64; k <<= 1) {
#pragma unroll
      for (int j = 32; j >= 1; j >>= 1) {
        if (j >= k) continue;
        int other = __shfl_xor(key, j, 64);
        bool lower = ((lane & j) == 0);
        bool asc = ((lane & k) == 0);
        int mn = (key < other) ? key : other;
        int mx = (key < other) ? other : key;
        key = (lower == asc) ? mn : mx;
      }
    }
    if (lane < n) elist[s0 + lane] = key;
  } else if (lane == 0) {
    for (int i = s0 + 1; i < s1; ++i) {
      int v = elist[i]; int j = i - 1;
      while (j >= s0 && elist[j] > v) { elist[j + 1] = elist[j]; --j; }
      elist[j + 1] = v;
    }
  }
}

// --------------------------------------- weight transpose + bf16 conversion
__global__ __launch_bounds__(256) void wcvt_kernel(
    const float* __restrict__ W, unsigned short* __restrict__ BT,
    int K, int Kpad, int lsW, int lsBT, int rowoff) {
  __shared__ unsigned short t[64][65];
  const int l = blockIdx.x, k0 = blockIdx.y * 64, n0 = blockIdx.z * 64;
  const int tid = threadIdx.x, tc = tid & 63, tr = tid >> 6;
  const float* Wl = W + (size_t)l * lsW + (size_t)rowoff * 256;
  unsigned short* BTl = BT + (size_t)l * lsBT;
  for (int r = tr; r < 64; r += 4) {
    int k = k0 + r;
    float v = (k < K) ? Wl[(size_t)k * 256 + n0 + tc] : 0.f;
    t[r][tc] = f2bf(v);
  }
  __syncthreads();
  for (int r = tr; r < 64; r += 4) {
    int n = n0 + r, k = k0 + tc;
    if (k < Kpad) BTl[(size_t)n * Kpad + k] = t[tc][r];
  }
}

// ---------------------------------------------------------------- encoder
__global__ __launch_bounds__(256) void enc_kernel(
    const float* __restrict__ pos, const float* __restrict__ W,
    const float* __restrict__ b, float* __restrict__ h,
    unsigned short* __restrict__ hb) {
  const int gidx = blockIdx.x * 256 + threadIdx.x;
  const int node = gidx >> 8, c = gidx & 255;
  float v = pos[node * 3 + 0] * W[c] + pos[node * 3 + 1] * W[HH + c] +
            pos[node * 3 + 2] * W[2 * HH + c] + b[c];
  h[gidx] = v;
  hb[gidx] = f2bf(v);
}

// ------------------------------------------------- PQ (layer 0 bootstrap)
__global__ __launch_bounds__(256, 2) void pq_mfma(
    const unsigned short* __restrict__ hb, float* __restrict__ P,
    unsigned short* __restrict__ Qb,
    const unsigned short* __restrict__ BT2, const float* __restrict__ mb) {
  __shared__ __align__(16) unsigned short A[16 * RPQ];
  const int tid = threadIdx.x;
  const int base = blockIdx.x * 16;
  const int lane = tid & 63, wv = tid >> 6;
  for (int it = 0; it < 4; ++it) {
    int row = it * 4 + wv;
    ushort4 v = *(const ushort4*)(hb + (size_t)(base + row) * HH + lane * 4);
    *(ushort4*)&A[row * RPQ + lane * 4] = v;
  }
  __syncthreads();
  const int m = lane & 15, g = lane >> 4;
  const int n0 = wv * 128;
  f32x4 acc[8] = {};
  const unsigned short* ap = A + m * RPQ + g * 8;
  const unsigned short* bp = BT2 + (size_t)(n0 + m) * 256 + g * 8;
  for (int ks = 0; ks < 8; ++ks) {
    const int ko = ks * 32;
    short8 a = *(const short8*)(ap + ko);
#pragma unroll
    for (int t = 0; t < 8; ++t)
      acc[t] = __builtin_amdgcn_mfma_f32_16x16x32_bf16(
          a, *(const short8*)(bp + (size_t)t * 16 * 256 + ko), acc[t], 0, 0, 0);
  }
#pragma unroll
  for (int t = 0; t < 8; ++t) {
    int c = n0 + t * 16 + m;
#pragma unroll
    for (int i = 0; i < 4; ++i) {
      int row = base + g * 4 + i;
      if (c < 256) P[(size_t)row * 256 + c] = acc[t][i] + mb[c];
      else Qb[(size_t)row * 256 + (c - 256)] = f2bf(acc[t][i]);
    }
  }
}

// ------------------------------------------------- edge pass (standalone)
// 2-edge ILP batch: edges e and e+ESPL computed together; their four
// shuffle-reduce chains interleave (4-way ILP per level). Accumulation
// order preserved (A then B ascending) -> bit-identical to the serial form.
__global__ __launch_bounds__(256) void msg_edge(
    const float* __restrict__ Pin, const unsigned short* __restrict__ Qbin,
    float* __restrict__ agg,
    const int* __restrict__ elist, const int* __restrict__ offs,
    const float* __restrict__ invd, const float* __restrict__ ea,
    const float* __restrict__ msgWl, const float* __restrict__ mg,
    const float* __restrict__ mbt) {
  __shared__ float part[DPB][ESPL][256];
  const int tid = threadIdx.x;
  const int hh = tid & 31;
  const int gid = tid >> 5;
  const int dl = gid >> 2;
  const int sp = gid & 3;
  const int d = blockIdx.x * DPB + dl;
  const int c0 = hh * 8;
  float we[4][8], gg[8], bt[8], p[8], acc8[8];
#pragma unroll
  for (int j = 0; j < 4; ++j) {
    *(float4*)&we[j][0] = *(const float4*)(msgWl + (size_t)(512 + j) * 256 + c0);
    *(float4*)&we[j][4] = *(const float4*)(msgWl + (size_t)(512 + j) * 256 + c0 + 4);
  }
  *(float4*)&gg[0] = *(const float4*)(mg + c0);
  *(float4*)&gg[4] = *(const float4*)(mg + c0 + 4);
  *(float4*)&bt[0] = *(const float4*)(mbt + c0);
  *(float4*)&bt[4] = *(const float4*)(mbt + c0 + 4);
  *(float4*)&p[0] = *(const float4*)(Pin + (size_t)d * 256 + c0);
  *(float4*)&p[4] = *(const float4*)(Pin + (size_t)d * 256 + c0 + 4);
#pragma unroll
  for (int k = 0; k < 8; ++k) acc8[k] = 0.f;
  const int s0 = offs[d];
  const int n = offs[d + 1] - s0;
  float4 eaA = {0, 0, 0, 0}, eaB = {0, 0, 0, 0};
  short8 qA8 = {}, qB8 = {};
  if (sp < n) {
    int eid = elist[s0 + sp];
    eaA = *(const float4*)(ea + (size_t)eid * 4);
    qA8 = *(const short8*)(Qbin + (size_t)(eid / KX) * 256 + c0);
  }
  if (sp + ESPL < n) {
    int eid = elist[s0 + sp + ESPL];
    eaB = *(const float4*)(ea + (size_t)eid * 4);
    qB8 = *(const short8*)(Qbin + (size_t)(eid / KX) * 256 + c0);
  }
  for (int e = sp; e < n; e += 2 * ESPL) {
    // prefetch the next batch (e+2E, e+3E)
    float4 eaC = {0, 0, 0, 0}, eaD = {0, 0, 0, 0};
    short8 qC8 = {}, qD8 = {};
    if (e + 2 * ESPL < n) {
      int eid = elist[s0 + e + 2 * ESPL];
      eaC = *(const float4*)(ea + (size_t)eid * 4);
      qC8 = *(const short8*)(Qbin + (size_t)(eid / KX) * 256 + c0);
    }
    if (e + 3 * ESPL < n) {
      int eid = elist[s0 + e + 3 * ESPL];
      eaD = *(const float4*)(ea + (size_t)eid * 4);
      qD8 = *(const short8*)(Qbin + (size_t)(eid / KX) * 256 + c0);
    }
    const bool haveB = (e + ESPL < n);
    float vA[8], vB[8];
    float sA = 0.f, s2A = 0.f, sB = 0.f, s2B = 0.f;
#pragma unroll
    for (int k = 0; k < 8; ++k) {
      float qk = bf2f((unsigned short)qA8[k]);
      float z = p[k] + qk + eaA.x * we[0][k] + eaA.y * we[1][k] +
                eaA.z * we[2][k] + eaA.w * we[3][k];
      z = fmaxf(z, 0.f);
      vA[k] = z; sA += z; s2A += z * z;
      float qk2 = bf2f((unsigned short)qB8[k]);
      float z2 = p[k] + qk2 + eaB.x * we[0][k] + eaB.y * we[1][k] +
                 eaB.z * we[2][k] + eaB.w * we[3][k];
      z2 = fmaxf(z2, 0.f);
      vB[k] = z2; sB += z2; s2B += z2 * z2;
    }
    // interleaved 32-lane reduces: 4 independent chains per level
#pragma unroll
    for (int o = 1; o < 32; o <<= 1) {
      sA += __shfl_xor(sA, o, 64);
      s2A += __shfl_xor(s2A, o, 64);
      sB += __shfl_xor(sB, o, 64);
      s2B += __shfl_xor(s2B, o, 64);
    }
    {
      const float mu = sA * (1.f / HH);
      const float rs = rsqrtf(s2A * (1.f / HH) - mu * mu + 1e-5f);
#pragma unroll
      for (int k = 0; k < 8; ++k) acc8[k] += (vA[k] - mu) * rs * gg[k] + bt[k];
    }
    if (haveB) {
      const float mu = sB * (1.f / HH);
      const float rs = rsqrtf(s2B * (1.f / HH) - mu * mu + 1e-5f);
#pragma unroll
      for (int k = 0; k < 8; ++k) acc8[k] += (vB[k] - mu) * rs * gg[k] + bt[k];
    }
    eaA = eaC; qA8 = qC8;
    eaB = eaD; qB8 = qD8;
  }
  *(float4*)&part[dl][sp][c0] = *(float4*)&acc8[0];
  *(float4*)&part[dl][sp][c0 + 4] = *(float4*)&acc8[4];
  __syncthreads();
  if (sp == 0) {
    const float iv = invd[d];
#pragma unroll
    for (int k = 0; k < 8; ++k) {
      int c = c0 + k;
      float sval = ((part[dl][0][c] + part[dl][1][c]) + part[dl][2][c]) + part[dl][3][c];
      agg[(size_t)d * 256 + c] = sval * iv;
    }
  }
}

// ------------------------------------------------- upd + next-PQ (fused)
__global__ __launch_bounds__(256, 3) void updpq_mfma(
    float* __restrict__ h, unsigned short* __restrict__ hb,
    const float* __restrict__ agg, float* __restrict__ Pout,
    unsigned short* __restrict__ Qbout,
    const unsigned short* __restrict__ uBTl, const float* __restrict__ ub,
    const float* __restrict__ ug, const float* __restrict__ ubt,
    const unsigned short* __restrict__ nextBT2,
    const float* __restrict__ nextmb, int has_next) {
  __shared__ __align__(16) unsigned short feat[8 * RPADU];
  __shared__ __align__(16) unsigned short hsh[8 * RH];
  __shared__ float psum[8][4], psum2[8][4], smu[8], srs[8];
  const int tid = threadIdx.x;
  const int base = blockIdx.x * 8;
  for (int it = 0; it < 4; ++it) {
    int idx = it * 256 + tid;
    int row = idx >> 7, ps = (idx & 127) * 4;
    int node = base + row;
    ushort4 o;
    if (ps < 256) {
      o = *(const ushort4*)(hb + (size_t)node * HH + ps);
    } else {
      float4 a4 = *(const float4*)(agg + (size_t)node * HH + (ps - 256));
      o.x = f2bf(a4.x); o.y = f2bf(a4.y); o.z = f2bf(a4.z); o.w = f2bf(a4.w);
    }
    *(ushort4*)&feat[row * RPADU + ps] = o;
  }
  __syncthreads();
  const int lane = tid & 63, wv = tid >> 6;
  const int m = lane & 15, g = lane >> 4;
  const int n0 = wv * 64;
  {
    f32x4 acc[4] = {};
    const unsigned short* ap = feat + (m & 7) * RPADU + g * 8;
    const unsigned short* bp0 = uBTl + (size_t)(n0 + m) * KPADU + g * 8;
    const unsigned short* bp1 = bp0 + 16 * KPADU;
    const unsigned short* bp2 = bp0 + 32 * KPADU;
    const unsigned short* bp3 = bp0 + 48 * KPADU;
    for (int ks = 0; ks < 16; ++ks) {
      const int ko = ks * 32;
      short8 a = *(const short8*)(ap + ko);
      acc[0] = __builtin_amdgcn_mfma_f32_16x16x32_bf16(a, *(const short8*)(bp0 + ko), acc[0], 0, 0, 0);
      acc[1] = __builtin_amdgcn_mfma_f32_16x16x32_bf16(a, *(const short8*)(bp1 + ko), acc[1], 0, 0, 0);
      acc[2] = __builtin_amdgcn_mfma_f32_16x16x32_bf16(a, *(const short8*)(bp2 + ko), acc[2], 0, 0, 0);
      acc[3] = __builtin_amdgcn_mfma_f32_16x16x32_bf16(a, *(const short8*)(bp3 + ko), acc[3], 0, 0, 0);
    }
    float bb[4], gg4[4], be4[4];
#pragma unroll
    for (int nt = 0; nt < 4; ++nt) {
      int c = n0 + nt * 16 + m;
      bb[nt] = ub[c]; gg4[nt] = ug[c]; be4[nt] = ubt[c];
    }
#pragma unroll
    for (int i = 0; i < 4; ++i) {
      float s = 0.f, s2 = 0.f;
#pragma unroll
      for (int nt = 0; nt < 4; ++nt) {
        float v = fmaxf(acc[nt][i] + bb[nt], 0.f);
        acc[nt][i] = v; s += v; s2 += v * v;
      }
#pragma unroll
      for (int o = 1; o < 16; o <<= 1) {
        s += __shfl_xor(s, o, 64);
        s2 += __shfl_xor(s2, o, 64);
      }
      if (m == 0 && g < 2) { int e = g * 4 + i; psum[e][wv] = s; psum2[e][wv] = s2; }
    }
    __syncthreads();
    if (tid < 8) {
      float s = psum[tid][0] + psum[tid][1] + psum[tid][2] + psum[tid][3];
      float s2 = psum2[tid][0] + psum2[tid][1] + psum2[tid][2] + psum2[tid][3];
      float mu = s * (1.f / HH);
      smu[tid] = mu;
      srs[tid] = rsqrtf(s2 * (1.f / HH) - mu * mu + 1e-5f);
    }
    __syncthreads();
    if (g < 2) {
#pragma unroll
      for (int i = 0; i < 4; ++i) {
        int e = g * 4 + i;
        int node = base + e;
        float mu = smu[e], rs = srs[e];
#pragma unroll
        for (int nt = 0; nt < 4; ++nt) {
          int c = n0 + nt * 16 + m;
          float u = (acc[nt][i] - mu) * rs * gg4[nt] + be4[nt];
          float hn = h[(size_t)node * HH + c] + u;
          h[(size_t)node * HH + c] = hn;
          unsigned short hv = f2bf(hn);
          hb[(size_t)node * HH + c] = hv;
          hsh[e * RH + c] = hv;
        }
      }
    }
  }
  if (has_next) {
    __syncthreads();
    f32x4 pacc[8] = {};
    const unsigned short* ap3 = hsh + (m & 7) * RH + g * 8;
    const unsigned short* bp3 = nextBT2 + (size_t)(wv * 128 + m) * 256 + g * 8;
    for (int ks = 0; ks < 8; ++ks) {
      const int ko = ks * 32;
      short8 a = *(const short8*)(ap3 + ko);
#pragma unroll
      for (int t = 0; t < 8; ++t)
        pacc[t] = __builtin_amdgcn_mfma_f32_16x16x32_bf16(
            a, *(const short8*)(bp3 + (size_t)t * 16 * 256 + ko), pacc[t], 0, 0, 0);
    }
    if (g < 2) {
#pragma unroll
      for (int t = 0; t < 8; ++t) {
        int c = wv * 128 + t * 16 + m;
#pragma unroll
        for (int i = 0; i < 4; ++i) {
          int row = base + g * 4 + i;
          if (c < 256) Pout[(size_t)row * 256 + c] = pacc[t][i] + nextmb[c];
          else Qbout[(size_t)row * 256 + (c - 256)] = f2bf(pacc[t][i]);
        }
      }
    }
  }
}

// ---------------------------------------------------------------- projection
__global__ __launch_bounds__(256) void proj_kernel(
    const float* __restrict__ h,
    const float* __restrict__ W1, const float* __restrict__ b1,
    const float* __restrict__ W2, const float* __restrict__ b2,
    float* __restrict__ out) {
  __shared__ float sh[8][256];
  __shared__ float st[8][256];
  const int tid = threadIdx.x, base = blockIdx.x * 8;
  for (int i = 0; i < 8; ++i) sh[i][tid] = h[(size_t)(base + i) * HH + tid];
  __syncthreads();
  {
    float acc[8] = {};
    for (int k = 0; k < 256; ++k) {
      const float w = W1[(size_t)k * 256 + tid];
#pragma unroll
      for (int r = 0; r < 8; ++r) acc[r] += sh[r][k] * w;
    }
    const float b = b1[tid];
#pragma unroll
    for (int r = 0; r < 8; ++r) st[r][tid] = fmaxf(acc[r] + b, 0.f);
  }
  __syncthreads();
  {
    const int c = tid & 127;
    const int half = tid >> 7;
    float acc2[4] = {};
    for (int k = 0; k < 256; ++k) {
      const float w = W2[(size_t)k * PP + c];
#pragma unroll
      for (int r = 0; r < 4; ++r) acc2[r] += st[half * 4 + r][k] * w;
    }
    const float b = b2[c];
#pragma unroll
    for (int r = 0; r < 4; ++r)
      out[(size_t)(base + half * 4 + r) * PP + c] = acc2[r] + b;
  }
}

// ---------------------------------------------------------------- launcher
extern "C" void kernel_launch(void* const* d_in, const int* in_sizes, int n_in,
                              void* d_out, int out_size, void* d_ws, size_t ws_size,
                              hipStream_t stream) {
  const float* pos   = (const float*)d_in[0];
  const float* box   = (const float*)d_in[1];
  const float* encW  = (const float*)d_in[2];
  const float* encB  = (const float*)d_in[3];
  const float* msgW  = (const float*)d_in[4];
  const float* msgB  = (const float*)d_in[5];
  const float* msgG  = (const float*)d_in[6];
  const float* msgBt = (const float*)d_in[7];
  const float* updW  = (const float*)d_in[8];
  const float* updB  = (const float*)d_in[9];
  const float* updG  = (const float*)d_in[10];
  const float* updBt = (const float*)d_in[11];
  const float* pW1   = (const float*)d_in[12];
  const float* pb1   = (const float*)d_in[13];
  const float* pW2   = (const float*)d_in[14];
  const float* pb2   = (const float*)d_in[15];
  float* out = (float*)d_out;

  char* w = (char*)d_ws;
  auto alloc = [&](size_t bytes) {
    char* p = w;
    w += (bytes + 255) & ~(size_t)255;
    return p;
  };
  int*   nbr    = (int*)alloc((size_t)EE * 4);
  float* ea     = (float*)alloc((size_t)EE * 16);
  int*   counts = (int*)alloc((size_t)NN * 4);
  int*   offs   = (int*)alloc((size_t)(NN + 1) * 4);
  int*   cursor = (int*)alloc((size_t)NN * 4);
  int*   elist  = (int*)alloc((size_t)EE * 4);
  float* invd   = (float*)alloc((size_t)NN * 4);
  float* hbuf   = (float*)alloc((size_t)NN * HH * 4);
  float* agg    = (float*)alloc((size_t)NN * HH * 4);
  float* P0     = (float*)alloc((size_t)NN * 256 * 4);
  float* P1     = (float*)alloc((size_t)NN * 256 * 4);
  float4* pos4  = (float4*)alloc((size_t)NN * 16);
  unsigned short* Qb0  = (unsigned short*)alloc((size_t)NN * 256 * 2);
  unsigned short* Qb1  = (unsigned short*)alloc((size_t)NN * 256 * 2);
  unsigned short* hb   = (unsigned short*)alloc((size_t)NN * HH * 2);
  unsigned short* mBT2 = (unsigned short*)alloc((size_t)LL * 512 * 256 * 2);
  unsigned short* uBT  = (unsigned short*)alloc((size_t)LL * 256 * KPADU * 2);

  hipMemsetAsync(counts, 0, (size_t)NN * 4, stream);
  hipMemsetAsync(cursor, 0, (size_t)NN * 4, stream);

  wcvt_kernel<<<dim3(LL, 4, 4), 256, 0, stream>>>(
      msgW, mBT2, 256, 256, 516 * 256, 512 * 256, 0);
  wcvt_kernel<<<dim3(LL, 4, 4), 256, 0, stream>>>(
      msgW, mBT2 + 256 * 256, 256, 256, 516 * 256, 512 * 256, 256);
  wcvt_kernel<<<dim3(LL, 8, 4), 256, 0, stream>>>(
      updW, uBT, 512, 512, 512 * 256, 256 * 512, 0);

  pos4_kernel<<<(NN + 255) / 256, 256, 0, stream>>>(pos, pos4);
  knn_kernel<<<NN, 256, 0, stream>>>(pos4, box, nbr, ea, counts);
  offsets_kernel<<<1, 256, 0, stream>>>(counts, offs, invd);
  scatter_kernel<<<(EE + 255) / 256, 256, 0, stream>>>(nbr, offs, cursor, elist);
  sortlists_kernel<<<(NN + 3) / 4, 256, 0, stream>>>(offs, elist);
  enc_kernel<<<NN, 256, 0, stream>>>(pos, encW, encB, hbuf, hb);
  pq_mfma<<<NN / 16, 256, 0, stream>>>(hb, P0, Qb0, mBT2, msgB);

  for (int l = 0; l < LL; ++l) {
    const int hn = (l + 1 < LL) ? 1 : 0;
    float* Pin  = (l & 1) ? P1 : P0;
    float* Pout = (l & 1) ? P0 : P1;
    unsigned short* Qbin  = (l & 1) ? Qb1 : Qb0;
    unsigned short* Qbout = (l & 1) ? Qb0 : Qb1;
    msg_edge<<<NN / DPB, 256, 0, stream>>>(
        Pin, Qbin, agg, elist, offs, invd, ea,
        msgW + (size_t)l * 516 * 256,
        msgG + (size_t)l * HH, msgBt + (size_t)l * HH);
    updpq_mfma<<<NN / 8, 256, 0, stream>>>(
        hbuf, hb, agg, Pout, Qbout,
        uBT + (size_t)l * 256 * KPADU,
        updB + (size_t)l * HH, updG + (size_t)l * HH, updBt + (size_t)l * HH,
        mBT2 + (size_t)(hn ? (l + 1) : 0) * 512 * 256,
        msgB + (size_t)(hn ? (l + 1) : 0) * HH, hn);
  }
  proj_kernel<<<NN / 8, 256, 0, stream>>>(hbuf, pW1, pb1, pW2, pb2, out);
}

// Round 24
// 1062.031 us; speedup vs baseline: 1.0434x; 1.0434x over previous
//
#include <hip/hip_runtime.h>

#define NN 6000
#define HH 256
#define LL 10
#define KX 30
#define PP 128
#define EE (NN * KX)
#define KPADU 512    // upd BT row length
#define RPADU 520    // upd A row stride (ushorts)
#define RPQ 264      // pq A-tile row stride (ushorts)
#define RH 264       // hsh row stride (ushorts)
#define NBINS 1024
#define BINSCALE 32768.0f   // 2^15: exact fp32 scale; covers d2 < 0.03125
#define CAP 64
#define ESPL 4       // edge-split groups per dst
#define DPB 2        // dst per msg_edge block

typedef __attribute__((ext_vector_type(8))) short short8;
typedef __attribute__((ext_vector_type(4))) float f32x4;

__device__ __forceinline__ unsigned short f2bf(float x) {
  union { float f; unsigned u; } v; v.f = x;
  return (unsigned short)((v.u + 0x7fffu + ((v.u >> 16) & 1u)) >> 16);
}
__device__ __forceinline__ float bf2f(unsigned short u) {
  union { unsigned u32; float f; } v; v.u32 = ((unsigned)u) << 16; return v.f;
}

// --------------------------------------------------------- pos -> float4
__global__ __launch_bounds__(256) void pos4_kernel(
    const float* __restrict__ pos, float4* __restrict__ pos4) {
  const int j = blockIdx.x * 256 + threadIdx.x;
  if (j >= NN) return;
  float4 p; p.x = pos[j * 3 + 0]; p.y = pos[j * 3 + 1]; p.z = pos[j * 3 + 2];
  p.w = 0.f;
  pos4[j] = p;
}

// ---------------------------------------------------------------- kNN
__global__ __launch_bounds__(256) void knn_kernel(
    const float4* __restrict__ pos4, const float* __restrict__ box,
    int* __restrict__ nbr, float* __restrict__ ea, int* __restrict__ counts) {
  __shared__ int hist[NBINS];
  __shared__ int sum4[256];
  __shared__ unsigned long long cand[CAP];
  __shared__ int cnt;
  __shared__ float Tsh;
  __shared__ float wvv[4];
  __shared__ int wvi[4];
  const int a = blockIdx.x, tid = threadIdx.x;
  const int lane = tid & 63, wv = tid >> 6;
  const float bx = box[0], by = box[1], bz = box[2];
  const float ibx = 1.0f / bx, iby = 1.0f / by, ibz = 1.0f / bz;
  const float4 pa = pos4[a];
  const float pax = pa.x, pay = pa.y, paz = pa.z;
  for (int i = tid; i < NBINS; i += 256) hist[i] = 0;
  if (tid == 0) cnt = 0;
  __syncthreads();
  float v[24];
#pragma unroll
  for (int q = 0; q < 24; ++q) {
    int j = tid + (q << 8);
    float d2 = 3e38f;
    if (j < NN && j != a) {
      float4 pj = pos4[j];
      float dx = pax - pj.x; dx -= rintf(dx * ibx) * bx;
      float dy = pay - pj.y; dy -= rintf(dy * iby) * by;
      float dz = paz - pj.z; dz -= rintf(dz * ibz) * bz;
      d2 = dx * dx + dy * dy + dz * dz;
    }
    v[q] = d2;
    if (d2 < 0.03125f) atomicAdd(&hist[(int)(d2 * BINSCALE)], 1);
  }
  __syncthreads();
  // parallel 4-bin pre-sums, then wave-0 scan (4 LDS reads/lane instead of 16)
  sum4[tid] = hist[tid * 4 + 0] + hist[tid * 4 + 1] +
              hist[tid * 4 + 2] + hist[tid * 4 + 3];
  __syncthreads();
  if (wv == 0) {
    int loc = sum4[lane * 4 + 0] + sum4[lane * 4 + 1] +
              sum4[lane * 4 + 2] + sum4[lane * 4 + 3];
    int inc = loc;
#pragma unroll
    for (int o = 1; o < 64; o <<= 1) {
      int t = __shfl_up(inc, o, 64);
      if (lane >= o) inc += t;
    }
    unsigned long long m = __ballot(inc >= KX);
    if (m == 0) {
      if (lane == 0) Tsh = -1.f;
    } else {
      int l0 = __ffsll(m) - 1;
      if (lane == l0) {
        int run = inc - loc;
        int B = l0 * 16;
        for (int i = 0; i < 16; ++i) {
          run += hist[l0 * 16 + i];
          if (run >= KX) { B = l0 * 16 + i; break; }
        }
        Tsh = (float)(B + 1) * (1.0f / BINSCALE);
      }
    }
  }
  __syncthreads();
  const float T = Tsh;
  if (T > 0.f) {
#pragma unroll
    for (int q = 0; q < 24; ++q) {
      if (v[q] < T) {
        int idx = atomicAdd(&cnt, 1);
        if (idx < CAP)
          cand[idx] = ((unsigned long long)__float_as_uint(v[q]) << 32) |
                      (unsigned)(tid + (q << 8));
      }
    }
    __syncthreads();
  }
  const int nc = cnt;
  const bool fast = (T > 0.f) && (nc >= KX) && (nc <= CAP);
  if (fast) {
    if (wv == 0) {
      unsigned long long key = (lane < nc) ? cand[lane] : ~0ull;
#pragma unroll
      for (int k = 2; k <= 64; k <<= 1) {
#pragma unroll
        for (int j = 32; j >= 1; j >>= 1) {
          if (j >= k) continue;
          unsigned long long other = __shfl_xor(key, j, 64);
          bool lower = ((lane & j) == 0);
          bool asc = ((lane & k) == 0);
          unsigned long long mn = (key < other) ? key : other;
          unsigned long long mx = (key < other) ? other : key;
          key = (lower == asc) ? mn : mx;
        }
      }
      if (lane < KX) {
        int b = (int)(key & 0xffffffffu);
        float d2 = __uint_as_float((unsigned)(key >> 32));
        float4 pb = pos4[b];
        float dx = pax - pb.x; dx -= rintf(dx * ibx) * bx;
        float dy = pay - pb.y; dy -= rintf(dy * iby) * by;
        float dz = paz - pb.z; dz -= rintf(dz * ibz) * bz;
        nbr[a * KX + lane] = b;
        float4 e4; e4.x = dx; e4.y = dy; e4.z = dz; e4.w = sqrtf(d2);
        *(float4*)&ea[(a * KX + lane) * 4] = e4;
        atomicAdd(&counts[b], 1);
      }
    }
  } else {
    // deterministic fallback: original 30-round argmin
    float lmin = v[0]; int larg = tid;
#pragma unroll
    for (int q = 1; q < 24; ++q) {
      int j = tid + (q << 8);
      if (v[q] < lmin) { lmin = v[q]; larg = j; }
    }
    for (int r = 0; r < KX; ++r) {
      float m = lmin; int ar = larg;
#pragma unroll
      for (int o = 1; o < 64; o <<= 1) {
        float m2 = __shfl_xor(m, o, 64);
        int a2 = __shfl_xor(ar, o, 64);
        if (m2 < m || (m2 == m && a2 < ar)) { m = m2; ar = a2; }
      }
      if (lane == 0) { wvv[wv] = m; wvi[wv] = ar; }
      __syncthreads();
      float gm = wvv[0]; int ga = wvi[0];
#pragma unroll
      for (int w2 = 1; w2 < 4; ++w2) {
        float m2 = wvv[w2]; int a2 = wvi[w2];
        if (m2 < gm || (m2 == gm && a2 < ga)) { gm = m2; ga = a2; }
      }
      if (tid == 0) {
        int b = ga;
        nbr[a * KX + r] = b;
        float4 pb = pos4[b];
        float dx = pax - pb.x; dx -= rintf(dx * ibx) * bx;
        float dy = pay - pb.y; dy -= rintf(dy * iby) * by;
        float dz = paz - pb.z; dz -= rintf(dz * ibz) * bz;
        float4 e4; e4.x = dx; e4.y = dy; e4.z = dz; e4.w = sqrtf(gm);
        *(float4*)&ea[(a * KX + r) * 4] = e4;
        atomicAdd(&counts[b], 1);
      }
      if ((ga & 255) == tid) {
        const int qq = ga >> 8;
#pragma unroll
        for (int q = 0; q < 24; ++q) if (q == qq) v[q] = 3e38f;
        lmin = v[0]; larg = tid;
#pragma unroll
        for (int q = 1; q < 24; ++q) {
          int j = tid + (q << 8);
          if (v[q] < lmin) { lmin = v[q]; larg = j; }
        }
      }
      __syncthreads();
    }
  }
}

// ------------------------------------------------- CSR build (deterministic)
__global__ __launch_bounds__(256) void offsets_kernel(
    const int* __restrict__ counts, int* __restrict__ offs, float* __restrict__ invd) {
  __shared__ int ssum[256];
  const int t = threadIdx.x;
  const int lo = t * 24;
  int hi = lo + 24; if (hi > NN) hi = NN;
  int s = 0;
  for (int i = lo; i < hi; ++i) s += counts[i];
  ssum[t] = s;
  __syncthreads();
  for (int o = 1; o < 256; o <<= 1) {
    int v2 = (t >= o) ? ssum[t - o] : 0;
    __syncthreads();
    ssum[t] += v2;
    __syncthreads();
  }
  int run = ssum[t] - s;
  for (int i = lo; i < hi; ++i) { offs[i] = run; run += counts[i]; }
  if (t == 255) offs[NN] = run;
  for (int i = t; i < NN; i += 256) {
    float c = (float)counts[i];
    invd[i] = 1.0f / fmaxf(c, 1.0f);
  }
}

__global__ __launch_bounds__(256) void scatter_kernel(
    const int* __restrict__ nbr, const int* __restrict__ offs,
    int* __restrict__ cursor, int* __restrict__ elist) {
  const int e = blockIdx.x * 256 + threadIdx.x;
  if (e >= EE) return;
  const int d = nbr[e];
  const int slot = offs[d] + atomicAdd(&cursor[d], 1);
  elist[slot] = e;
}

// one 64-lane wave per dst: register bitonic sort of the (<=64) run.
__global__ __launch_bounds__(256) void sortlists_kernel(
    const int* __restrict__ offs, int* __restrict__ elist) {
  const int wv = threadIdx.x >> 6, lane = threadIdx.x & 63;
  const int d = blockIdx.x * 4 + wv;
  if (d >= NN) return;
  const int s0 = offs[d], s1 = offs[d + 1];
  const int n = s1 - s0;
  if (n <= 1) return;
  if (n <= 64) {
    int key = (lane < n) ? elist[s0 + lane] : 0x7fffffff;
#pragma unroll
    for (int k = 2; k <= 64; k <<= 1) {
#pragma unroll
      for (int j = 32; j >= 1; j >>= 1) {
        if (j >= k) continue;
        int other = __shfl_xor(key, j, 64);
        bool lower = ((lane & j) == 0);
        bool asc = ((lane & k) == 0);
        int mn = (key < other) ? key : other;
        int mx = (key < other) ? other : key;
        key = (lower == asc) ? mn : mx;
      }
    }
    if (lane < n) elist[s0 + lane] = key;
  } else if (lane == 0) {
    for (int i = s0 + 1; i < s1; ++i) {
      int v = elist[i]; int j = i - 1;
      while (j >= s0 && elist[j] > v) { elist[j + 1] = elist[j]; --j; }
      elist[j + 1] = v;
    }
  }
}

// --------------------------------------- weight transpose + bf16 conversion
__global__ __launch_bounds__(256) void wcvt_kernel(
    const float* __restrict__ W, unsigned short* __restrict__ BT,
    int K, int Kpad, int lsW, int lsBT, int rowoff) {
  __shared__ unsigned short t[64][65];
  const int l = blockIdx.x, k0 = blockIdx.y * 64, n0 = blockIdx.z * 64;
  const int tid = threadIdx.x, tc = tid & 63, tr = tid >> 6;
  const float* Wl = W + (size_t)l * lsW + (size_t)rowoff * 256;
  unsigned short* BTl = BT + (size_t)l * lsBT;
  for (int r = tr; r < 64; r += 4) {
    int k = k0 + r;
    float v = (k < K) ? Wl[(size_t)k * 256 + n0 + tc] : 0.f;
    t[r][tc] = f2bf(v);
  }
  __syncthreads();
  for (int r = tr; r < 64; r += 4) {
    int n = n0 + r, k = k0 + tc;
    if (k < Kpad) BTl[(size_t)n * Kpad + k] = t[tc][r];
  }
}

// ---------------------------------------------------------------- encoder
__global__ __launch_bounds__(256) void enc_kernel(
    const float* __restrict__ pos, const float* __restrict__ W,
    const float* __restrict__ b, float* __restrict__ h,
    unsigned short* __restrict__ hb) {
  const int gidx = blockIdx.x * 256 + threadIdx.x;
  const int node = gidx >> 8, c = gidx & 255;
  float v = pos[node * 3 + 0] * W[c] + pos[node * 3 + 1] * W[HH + c] +
            pos[node * 3 + 2] * W[2 * HH + c] + b[c];
  h[gidx] = v;
  hb[gidx] = f2bf(v);
}

// ------------------------------------------------- PQ (layer 0 bootstrap)
__global__ __launch_bounds__(256, 2) void pq_mfma(
    const unsigned short* __restrict__ hb, float* __restrict__ P,
    unsigned short* __restrict__ Qb,
    const unsigned short* __restrict__ BT2, const float* __restrict__ mb) {
  __shared__ __align__(16) unsigned short A[16 * RPQ];
  const int tid = threadIdx.x;
  const int base = blockIdx.x * 16;
  const int lane = tid & 63, wv = tid >> 6;
  for (int it = 0; it < 4; ++it) {
    int row = it * 4 + wv;
    ushort4 v = *(const ushort4*)(hb + (size_t)(base + row) * HH + lane * 4);
    *(ushort4*)&A[row * RPQ + lane * 4] = v;
  }
  __syncthreads();
  const int m = lane & 15, g = lane >> 4;
  const int n0 = wv * 128;
  f32x4 acc[8] = {};
  const unsigned short* ap = A + m * RPQ + g * 8;
  const unsigned short* bp = BT2 + (size_t)(n0 + m) * 256 + g * 8;
  for (int ks = 0; ks < 8; ++ks) {
    const int ko = ks * 32;
    short8 a = *(const short8*)(ap + ko);
#pragma unroll
    for (int t = 0; t < 8; ++t)
      acc[t] = __builtin_amdgcn_mfma_f32_16x16x32_bf16(
          a, *(const short8*)(bp + (size_t)t * 16 * 256 + ko), acc[t], 0, 0, 0);
  }
#pragma unroll
  for (int t = 0; t < 8; ++t) {
    int c = n0 + t * 16 + m;
#pragma unroll
    for (int i = 0; i < 4; ++i) {
      int row = base + g * 4 + i;
      if (c < 256) P[(size_t)row * 256 + c] = acc[t][i] + mb[c];
      else Qb[(size_t)row * 256 + (c - 256)] = f2bf(acc[t][i]);
    }
  }
}

// ------------------------------------------------- edge pass (standalone)
__global__ __launch_bounds__(256) void msg_edge(
    const float* __restrict__ Pin, const unsigned short* __restrict__ Qbin,
    float* __restrict__ agg,
    const int* __restrict__ elist, const int* __restrict__ offs,
    const float* __restrict__ invd, const float* __restrict__ ea,
    const float* __restrict__ msgWl, const float* __restrict__ mg,
    const float* __restrict__ mbt) {
  __shared__ float part[DPB][ESPL][256];
  const int tid = threadIdx.x;
  const int hh = tid & 31;
  const int gid = tid >> 5;
  const int dl = gid >> 2;
  const int sp = gid & 3;
  const int d = blockIdx.x * DPB + dl;
  const int c0 = hh * 8;
  float we[4][8], gg[8], bt[8], p[8], acc8[8];
#pragma unroll
  for (int j = 0; j < 4; ++j) {
    *(float4*)&we[j][0] = *(const float4*)(msgWl + (size_t)(512 + j) * 256 + c0);
    *(float4*)&we[j][4] = *(const float4*)(msgWl + (size_t)(512 + j) * 256 + c0 + 4);
  }
  *(float4*)&gg[0] = *(const float4*)(mg + c0);
  *(float4*)&gg[4] = *(const float4*)(mg + c0 + 4);
  *(float4*)&bt[0] = *(const float4*)(mbt + c0);
  *(float4*)&bt[4] = *(const float4*)(mbt + c0 + 4);
  *(float4*)&p[0] = *(const float4*)(Pin + (size_t)d * 256 + c0);
  *(float4*)&p[4] = *(const float4*)(Pin + (size_t)d * 256 + c0 + 4);
#pragma unroll
  for (int k = 0; k < 8; ++k) acc8[k] = 0.f;
  const int s0 = offs[d];
  const int n = offs[d + 1] - s0;
  float4 eaA = {0, 0, 0, 0}, eaB = {0, 0, 0, 0};
  short8 qA8 = {}, qB8 = {};
  if (sp < n) {
    int eid = elist[s0 + sp];
    eaA = *(const float4*)(ea + (size_t)eid * 4);
    qA8 = *(const short8*)(Qbin + (size_t)(eid / KX) * 256 + c0);
  }
  if (sp + ESPL < n) {
    int eid = elist[s0 + sp + ESPL];
    eaB = *(const float4*)(ea + (size_t)eid * 4);
    qB8 = *(const short8*)(Qbin + (size_t)(eid / KX) * 256 + c0);
  }
  for (int e = sp; e < n; e += ESPL) {
    float4 eaC = {0, 0, 0, 0};
    short8 qC8 = {};
    int eC = e + 2 * ESPL;
    if (eC < n) {
      int eid = elist[s0 + eC];
      eaC = *(const float4*)(ea + (size_t)eid * 4);
      qC8 = *(const short8*)(Qbin + (size_t)(eid / KX) * 256 + c0);
    }
    float v[8], s = 0.f, s2 = 0.f;
#pragma unroll
    for (int k = 0; k < 8; ++k) {
      float qk = bf2f((unsigned short)qA8[k]);
      float z = p[k] + qk + eaA.x * we[0][k] + eaA.y * we[1][k] +
                eaA.z * we[2][k] + eaA.w * we[3][k];
      z = fmaxf(z, 0.f);
      v[k] = z; s += z; s2 += z * z;
    }
#pragma unroll
    for (int o = 1; o < 32; o <<= 1) {
      s += __shfl_xor(s, o, 64);
      s2 += __shfl_xor(s2, o, 64);
    }
    const float mu = s * (1.f / HH);
    const float rs = rsqrtf(s2 * (1.f / HH) - mu * mu + 1e-5f);
#pragma unroll
    for (int k = 0; k < 8; ++k) acc8[k] += (v[k] - mu) * rs * gg[k] + bt[k];
    eaA = eaB; qA8 = qB8;
    eaB = eaC; qB8 = qC8;
  }
  *(float4*)&part[dl][sp][c0] = *(float4*)&acc8[0];
  *(float4*)&part[dl][sp][c0 + 4] = *(float4*)&acc8[4];
  __syncthreads();
  if (sp == 0) {
    const float iv = invd[d];
#pragma unroll
    for (int k = 0; k < 8; ++k) {
      int c = c0 + k;
      float sval = ((part[dl][0][c] + part[dl][1][c]) + part[dl][2][c]) + part[dl][3][c];
      agg[(size_t)d * 256 + c] = sval * iv;
    }
  }
}

// ------------------------------------------------- upd + next-PQ (fused)
__global__ __launch_bounds__(256, 3) void updpq_mfma(
    float* __restrict__ h, unsigned short* __restrict__ hb,
    const float* __restrict__ agg, float* __restrict__ Pout,
    unsigned short* __restrict__ Qbout,
    const unsigned short* __restrict__ uBTl, const float* __restrict__ ub,
    const float* __restrict__ ug, const float* __restrict__ ubt,
    const unsigned short* __restrict__ nextBT2,
    const float* __restrict__ nextmb, int has_next) {
  __shared__ __align__(16) unsigned short feat[8 * RPADU];
  __shared__ __align__(16) unsigned short hsh[8 * RH];
  __shared__ float psum[8][4], psum2[8][4], smu[8], srs[8];
  const int tid = threadIdx.x;
  const int base = blockIdx.x * 8;
  for (int it = 0; it < 4; ++it) {
    int idx = it * 256 + tid;
    int row = idx >> 7, ps = (idx & 127) * 4;
    int node = base + row;
    ushort4 o;
    if (ps < 256) {
      o = *(const ushort4*)(hb + (size_t)node * HH + ps);
    } else {
      float4 a4 = *(const float4*)(agg + (size_t)node * HH + (ps - 256));
      o.x = f2bf(a4.x); o.y = f2bf(a4.y); o.z = f2bf(a4.z); o.w = f2bf(a4.w);
    }
    *(ushort4*)&feat[row * RPADU + ps] = o;
  }
  __syncthreads();
  const int lane = tid & 63, wv = tid >> 6;
  const int m = lane & 15, g = lane >> 4;
  const int n0 = wv * 64;
  {
    f32x4 acc[4] = {};
    const unsigned short* ap = feat + (m & 7) * RPADU + g * 8;
    const unsigned short* bp0 = uBTl + (size_t)(n0 + m) * KPADU + g * 8;
    const unsigned short* bp1 = bp0 + 16 * KPADU;
    const unsigned short* bp2 = bp0 + 32 * KPADU;
    const unsigned short* bp3 = bp0 + 48 * KPADU;
    for (int ks = 0; ks < 16; ++ks) {
      const int ko = ks * 32;
      short8 a = *(const short8*)(ap + ko);
      acc[0] = __builtin_amdgcn_mfma_f32_16x16x32_bf16(a, *(const short8*)(bp0 + ko), acc[0], 0, 0, 0);
      acc[1] = __builtin_amdgcn_mfma_f32_16x16x32_bf16(a, *(const short8*)(bp1 + ko), acc[1], 0, 0, 0);
      acc[2] = __builtin_amdgcn_mfma_f32_16x16x32_bf16(a, *(const short8*)(bp2 + ko), acc[2], 0, 0, 0);
      acc[3] = __builtin_amdgcn_mfma_f32_16x16x32_bf16(a, *(const short8*)(bp3 + ko), acc[3], 0, 0, 0);
    }
    float bb[4], gg4[4], be4[4];
#pragma unroll
    for (int nt = 0; nt < 4; ++nt) {
      int c = n0 + nt * 16 + m;
      bb[nt] = ub[c]; gg4[nt] = ug[c]; be4[nt] = ubt[c];
    }
#pragma unroll
    for (int i = 0; i < 4; ++i) {
      float s = 0.f, s2 = 0.f;
#pragma unroll
      for (int nt = 0; nt < 4; ++nt) {
        float v = fmaxf(acc[nt][i] + bb[nt], 0.f);
        acc[nt][i] = v; s += v; s2 += v * v;
      }
#pragma unroll
      for (int o = 1; o < 16; o <<= 1) {
        s += __shfl_xor(s, o, 64);
        s2 += __shfl_xor(s2, o, 64);
      }
      if (m == 0 && g < 2) { int e = g * 4 + i; psum[e][wv] = s; psum2[e][wv] = s2; }
    }
    __syncthreads();
    if (tid < 8) {
      float s = psum[tid][0] + psum[tid][1] + psum[tid][2] + psum[tid][3];
      float s2 = psum2[tid][0] + psum2[tid][1] + psum2[tid][2] + psum2[tid][3];
      float mu = s * (1.f / HH);
      smu[tid] = mu;
      srs[tid] = rsqrtf(s2 * (1.f / HH) - mu * mu + 1e-5f);
    }
    __syncthreads();
    if (g < 2) {
#pragma unroll
      for (int i = 0; i < 4; ++i) {
        int e = g * 4 + i;
        int node = base + e;
        float mu = smu[e], rs = srs[e];
#pragma unroll
        for (int nt = 0; nt < 4; ++nt) {
          int c = n0 + nt * 16 + m;
          float u = (acc[nt][i] - mu) * rs * gg4[nt] + be4[nt];
          float hn = h[(size_t)node * HH + c] + u;
          h[(size_t)node * HH + c] = hn;
          unsigned short hv = f2bf(hn);
          hb[(size_t)node * HH + c] = hv;
          hsh[e * RH + c] = hv;
        }
      }
    }
  }
  if (has_next) {
    __syncthreads();
    f32x4 pacc[8] = {};
    const unsigned short* ap3 = hsh + (m & 7) * RH + g * 8;
    const unsigned short* bp3 = nextBT2 + (size_t)(wv * 128 + m) * 256 + g * 8;
    for (int ks = 0; ks < 8; ++ks) {
      const int ko = ks * 32;
      short8 a = *(const short8*)(ap3 + ko);
#pragma unroll
      for (int t = 0; t < 8; ++t)
        pacc[t] = __builtin_amdgcn_mfma_f32_16x16x32_bf16(
            a, *(const short8*)(bp3 + (size_t)t * 16 * 256 + ko), pacc[t], 0, 0, 0);
    }
    if (g < 2) {
#pragma unroll
      for (int t = 0; t < 8; ++t) {
        int c = wv * 128 + t * 16 + m;
#pragma unroll
        for (int i = 0; i < 4; ++i) {
          int row = base + g * 4 + i;
          if (c < 256) Pout[(size_t)row * 256 + c] = pacc[t][i] + nextmb[c];
          else Qbout[(size_t)row * 256 + (c - 256)] = f2bf(pacc[t][i]);
        }
      }
    }
  }
}

// ---------------------------------------------------------------- projection
__global__ __launch_bounds__(256) void proj_kernel(
    const float* __restrict__ h,
    const float* __restrict__ W1, const float* __restrict__ b1,
    const float* __restrict__ W2, const float* __restrict__ b2,
    float* __restrict__ out) {
  __shared__ float sh[8][256];
  __shared__ float st[8][256];
  const int tid = threadIdx.x, base = blockIdx.x * 8;
  for (int i = 0; i < 8; ++i) sh[i][tid] = h[(size_t)(base + i) * HH + tid];
  __syncthreads();
  {
    float acc[8] = {};
    for (int k = 0; k < 256; ++k) {
      const float w = W1[(size_t)k * 256 + tid];
#pragma unroll
      for (int r = 0; r < 8; ++r) acc[r] += sh[r][k] * w;
    }
    const float b = b1[tid];
#pragma unroll
    for (int r = 0; r < 8; ++r) st[r][tid] = fmaxf(acc[r] + b, 0.f);
  }
  __syncthreads();
  {
    const int c = tid & 127;
    const int half = tid >> 7;
    float acc2[4] = {};
    for (int k = 0; k < 256; ++k) {
      const float w = W2[(size_t)k * PP + c];
#pragma unroll
      for (int r = 0; r < 4; ++r) acc2[r] += st[half * 4 + r][k] * w;
    }
    const float b = b2[c];
#pragma unroll
    for (int r = 0; r < 4; ++r)
      out[(size_t)(base + half * 4 + r) * PP + c] = acc2[r] + b;
  }
}

// ---------------------------------------------------------------- launcher
extern "C" void kernel_launch(void* const* d_in, const int* in_sizes, int n_in,
                              void* d_out, int out_size, void* d_ws, size_t ws_size,
                              hipStream_t stream) {
  const float* pos   = (const float*)d_in[0];
  const float* box   = (const float*)d_in[1];
  const float* encW  = (const float*)d_in[2];
  const float* encB  = (const float*)d_in[3];
  const float* msgW  = (const float*)d_in[4];
  const float* msgB  = (const float*)d_in[5];
  const float* msgG  = (const float*)d_in[6];
  const float* msgBt = (const float*)d_in[7];
  const float* updW  = (const float*)d_in[8];
  const float* updB  = (const float*)d_in[9];
  const float* updG  = (const float*)d_in[10];
  const float* updBt = (const float*)d_in[11];
  const float* pW1   = (const float*)d_in[12];
  const float* pb1   = (const float*)d_in[13];
  const float* pW2   = (const float*)d_in[14];
  const float* pb2   = (const float*)d_in[15];
  float* out = (float*)d_out;

  char* w = (char*)d_ws;
  auto alloc = [&](size_t bytes) {
    char* p = w;
    w += (bytes + 255) & ~(size_t)255;
    return p;
  };
  int*   nbr    = (int*)alloc((size_t)EE * 4);
  float* ea     = (float*)alloc((size_t)EE * 16);
  int*   counts = (int*)alloc((size_t)NN * 4);
  int*   offs   = (int*)alloc((size_t)(NN + 1) * 4);
  int*   cursor = (int*)alloc((size_t)NN * 4);
  int*   elist  = (int*)alloc((size_t)EE * 4);
  float* invd   = (float*)alloc((size_t)NN * 4);
  float* hbuf   = (float*)alloc((size_t)NN * HH * 4);
  float* agg    = (float*)alloc((size_t)NN * HH * 4);
  float* P0     = (float*)alloc((size_t)NN * 256 * 4);
  float* P1     = (float*)alloc((size_t)NN * 256 * 4);
  float4* pos4  = (float4*)alloc((size_t)NN * 16);
  unsigned short* Qb0  = (unsigned short*)alloc((size_t)NN * 256 * 2);
  unsigned short* Qb1  = (unsigned short*)alloc((size_t)NN * 256 * 2);
  unsigned short* hb   = (unsigned short*)alloc((size_t)NN * HH * 2);
  unsigned short* mBT2 = (unsigned short*)alloc((size_t)LL * 512 * 256 * 2);
  unsigned short* uBT  = (unsigned short*)alloc((size_t)LL * 256 * KPADU * 2);

  hipMemsetAsync(counts, 0, (size_t)NN * 4, stream);
  hipMemsetAsync(cursor, 0, (size_t)NN * 4, stream);

  wcvt_kernel<<<dim3(LL, 4, 4), 256, 0, stream>>>(
      msgW, mBT2, 256, 256, 516 * 256, 512 * 256, 0);
  wcvt_kernel<<<dim3(LL, 4, 4), 256, 0, stream>>>(
      msgW, mBT2 + 256 * 256, 256, 256, 516 * 256, 512 * 256, 256);
  wcvt_kernel<<<dim3(LL, 8, 4), 256, 0, stream>>>(
      updW, uBT, 512, 512, 512 * 256, 256 * 512, 0);

  pos4_kernel<<<(NN + 255) / 256, 256, 0, stream>>>(pos, pos4);
  knn_kernel<<<NN, 256, 0, stream>>>(pos4, box, nbr, ea, counts);
  offsets_kernel<<<1, 256, 0, stream>>>(counts, offs, invd);
  scatter_kernel<<<(EE + 255) / 256, 256, 0, stream>>>(nbr, offs, cursor, elist);
  sortlists_kernel<<<(NN + 3) / 4, 256, 0, stream>>>(offs, elist);
  enc_kernel<<<NN, 256, 0, stream>>>(pos, encW, encB, hbuf, hb);
  pq_mfma<<<NN / 16, 256, 0, stream>>>(hb, P0, Qb0, mBT2, msgB);

  for (int l = 0; l < LL; ++l) {
    const int hn = (l + 1 < LL) ? 1 : 0;
    float* Pin  = (l & 1) ? P1 : P0;
    float* Pout = (l & 1) ? P0 : P1;
    unsigned short* Qbin  = (l & 1) ? Qb1 : Qb0;
    unsigned short* Qbout = (l & 1) ? Qb0 : Qb1;
    msg_edge<<<NN / DPB, 256, 0, stream>>>(
        Pin, Qbin, agg, elist, offs, invd, ea,
        msgW + (size_t)l * 516 * 256,
        msgG + (size_t)l * HH, msgBt + (size_t)l * HH);
    updpq_mfma<<<NN / 8, 256, 0, stream>>>(
        hbuf, hb, agg, Pout, Qbout,
        uBT + (size_t)l * 256 * KPADU,
        updB + (size_t)l * HH, updG + (size_t)l * HH, updBt + (size_t)l * HH,
        mBT2 + (size_t)(hn ? (l + 1) : 0) * 512 * 256,
        msgB + (size_t)(hn ? (l + 1) : 0) * HH, hn);
  }
  proj_kernel<<<NN / 8, 256, 0, stream>>>(hbuf, pW1, pb1, pW2, pb2, out);
}